// Round 6
// baseline (1409.874 us; speedup 1.0000x reference)
//
#include <hip/hip_runtime.h>
#include <float.h>

// ---------------------------------------------------------------------------
// OnlineClustering: normalize -> GEMM (bf16 MFMA; epilogue emits per-column
// online-softmax partials) -> merge (sh + dc1) -> Sinkhorn (factorized,
// WAVE-AUTONOMOUS passes: no block barriers in the main loop) -> out + loss.
//
// Fold C into the exponent: dc = EXPMAX + ln C;  ec = exp((l-sh)*TT_INV + dc).
//   w_s   = sum_k ec                (row sum)
//   u_k   = sum_s ec*R  (= C*t)  -> C' = C/(u+eps)  ==  dc' = dc - ln(u+eps)
//   out   = ec*R (last iteration)
// iter_k: 512 thr = 8 waves, 1 block/CU (96 KB LDS: sh, dc, transposed u).
// Each wave owns 4 rows; per row: 32 independent dwordx4 loads (deep ILP),
// intra-wave shfl_xor reduce, LDS ds_add u-update (transposed layout ->
// 2-way banks, free). Block syncs only at stage-in and u-flush.
// pp/pm (8 MB) and tpart (8 MB) live in d_out (dead until iter<1> writes it).
// ---------------------------------------------------------------------------

#define TT_INV 14.285714285714286f   // 1/0.07
#define TP_INV 8.333333333333334f    // 1/0.12
#define EXPMAX 50.0f
#define SK_EPS 1e-8f

typedef short v8s __attribute__((ext_vector_type(8)));
typedef float v4f __attribute__((ext_vector_type(4)));

__device__ inline unsigned short f2bf(float f){          // RNE float->bf16
  unsigned u = __float_as_uint(f);
  u += 0x7FFFu + ((u >> 16) & 1u);
  return (unsigned short)(u >> 16);
}

__device__ inline float wredsum(float v){
  #pragma unroll
  for(int o = 32; o; o >>= 1) v += __shfl_down(v, o);
  return v;
}

// block = 256 threads (4 waves) — used by norm_x only
__device__ inline float blockReduceSum(float v, float* sb){
  v = wredsum(v);
  __syncthreads();
  if((threadIdx.x & 63) == 0) sb[threadIdx.x >> 6] = v;
  __syncthreads();
  return (sb[0] + sb[1]) + (sb[2] + sb[3]);
}

__device__ inline void gl_lds16(const void* g, void* l){
  __builtin_amdgcn_global_load_lds(
      (const __attribute__((address_space(1))) void*)g,
      (__attribute__((address_space(3))) void*)l, 16, 0, 0);
}

// -------------------- init small buffers --------------------
__global__ __launch_bounds__(256) void init_k(float* __restrict__ Rb,
                                              float* __restrict__ lossacc){
  int i = blockIdx.x * 256 + threadIdx.x;   // grid covers 8192
  Rb[i] = 1.f;
  if(i == 0) lossacc[0] = 0.f;
}

// -------------------- normalize x rows, cast bf16 --------------------
__global__ __launch_bounds__(256) void norm_x_k(const float* __restrict__ x,
                                                unsigned short* __restrict__ xb){
  const int row = blockIdx.x, t = threadIdx.x;
  const float4 v = ((const float4*)(x + (size_t)row * 1024))[t];
  __shared__ float sb[4];
  float ss = v.x*v.x + v.y*v.y + v.z*v.z + v.w*v.w;
  float tot = blockReduceSum(ss, sb);
  float sc = 1.0f / fmaxf(sqrtf(tot), 1e-7f);
  ushort4 o = { f2bf(v.x*sc), f2bf(v.y*sc), f2bf(v.z*sc), f2bf(v.w*sc) };
  ((ushort4*)(xb + (size_t)row * 1024))[t] = o;
}

// -------------------- cast W bf16 --------------------
__global__ __launch_bounds__(256) void conv_w_k(const float* __restrict__ W,
                                                unsigned short* __restrict__ Wb){
  const size_t i = (size_t)blockIdx.x * 256 + threadIdx.x;
  const float4 v = ((const float4*)W)[i];
  ushort4 o = { f2bf(v.x), f2bf(v.y), f2bf(v.z), f2bf(v.w) };
  ((ushort4*)Wb)[i] = o;
}

// -------------------- bf16 GEMM (B^T form): C[m][n] = sum_d A[m][d]*B[n][d] --
// 128x128 block tile, BK=32, 4 waves each 64x64, global_load_lds width-16.
// Epilogue: per column, (max, sum exp) over this wave's 64 rows -> pp/pm[rh].
__global__ __launch_bounds__(256) void gemm_bt_k(const unsigned short* __restrict__ A,
                                                 const unsigned short* __restrict__ B,
                                                 float* __restrict__ C,
                                                 float* __restrict__ pp,
                                                 float* __restrict__ pm){
  __shared__ __align__(16) short As[128 * 32];
  __shared__ __align__(16) short Bs[128 * 32];
  const int t = threadIdx.x;
  const int L = t & 63, w = t >> 6;
  const int wm = w >> 1, wn = w & 1;
  const int quad = L >> 4, lr = L & 15;
  const int m0 = blockIdx.y * 128, n0 = blockIdx.x * 128;

  v4f acc[4][4];
  #pragma unroll
  for(int i = 0; i < 4; i++)
    #pragma unroll
    for(int j = 0; j < 4; j++) acc[i][j] = (v4f){0.f, 0.f, 0.f, 0.f};

  // staging chunks: 512 16B-chunks per tile, 2 per thread per tile
  const int c0 = t, c1 = t + 256;
  const int r0 = c0 >> 2, kc0 = c0 & 3;
  const int r1 = c1 >> 2, kc1 = c1 & 3;
  const unsigned short* gA0 = A + (size_t)(m0 + r0) * 1024 + kc0 * 8;
  const unsigned short* gA1 = A + (size_t)(m0 + r1) * 1024 + kc1 * 8;
  const unsigned short* gB0 = B + (size_t)(n0 + r0) * 1024 + kc0 * 8;
  const unsigned short* gB1 = B + (size_t)(n0 + r1) * 1024 + kc1 * 8;
  short* lA0 = &As[c0 * 8]; short* lA1 = &As[c1 * 8];
  short* lB0 = &Bs[c0 * 8]; short* lB1 = &Bs[c1 * 8];

  for(int kt = 0; kt < 32; ++kt){
    __syncthreads();
    const int ko = kt * 32;
    gl_lds16(gA0 + ko, lA0);
    gl_lds16(gA1 + ko, lA1);
    gl_lds16(gB0 + ko, lB0);
    gl_lds16(gB1 + ko, lB1);
    __syncthreads();
    v8s af[4], bf[4];
    #pragma unroll
    for(int mi = 0; mi < 4; mi++)
      af[mi] = *(const v8s*)&As[(wm*64 + mi*16 + lr) * 32 + quad * 8];
    #pragma unroll
    for(int ni = 0; ni < 4; ni++)
      bf[ni] = *(const v8s*)&Bs[(wn*64 + ni*16 + lr) * 32 + quad * 8];
    #pragma unroll
    for(int mi = 0; mi < 4; mi++)
      #pragma unroll
      for(int ni = 0; ni < 4; ni++)
        acc[mi][ni] = __builtin_amdgcn_mfma_f32_16x16x32_bf16(af[mi], bf[ni], acc[mi][ni], 0, 0, 0);
  }
  // C/D layout: col = lane&15, row = quad*4 + reg
  #pragma unroll
  for(int mi = 0; mi < 4; mi++){
    const int row = m0 + wm*64 + mi*16 + quad*4;
    #pragma unroll
    for(int ni = 0; ni < 4; ni++){
      const int col = n0 + wn*64 + ni*16 + lr;
      #pragma unroll
      for(int r = 0; r < 4; r++)
        C[(size_t)(row + r) * 8192 + col] = acc[mi][ni][r];
    }
  }
  // fused per-column online-softmax partial over this wave's 64 rows
  const int rh = blockIdx.y * 2 + wm;       // row-half index 0..127
  #pragma unroll
  for(int ni = 0; ni < 4; ni++){
    float m = acc[0][ni][0];
    #pragma unroll
    for(int mi = 0; mi < 4; mi++)
      #pragma unroll
      for(int r = 0; r < 4; r++) m = fmaxf(m, acc[mi][ni][r]);
    m = fmaxf(m, __shfl_xor(m, 16));
    m = fmaxf(m, __shfl_xor(m, 32));
    float p = 0.f;
    #pragma unroll
    for(int mi = 0; mi < 4; mi++)
      #pragma unroll
      for(int r = 0; r < 4; r++) p += __expf((acc[mi][ni][r] - m) * TT_INV);
    p += __shfl_xor(p, 16);
    p += __shfl_xor(p, 32);
    if(quad == 0){
      const int col = n0 + wn*64 + ni*16 + lr;
      pp[(size_t)rh * 8192 + col] = p;
      pm[(size_t)rh * 8192 + col] = m;
    }
  }
}

// -------------------- merge partials -> sh + dc1 --------------------
__global__ __launch_bounds__(256) void merge_k(const float* __restrict__ pp,
                                               const float* __restrict__ pm,
                                               float* __restrict__ shg,
                                               float* __restrict__ dcg){
  const int i = blockIdx.x * 256 + threadIdx.x;   // 0..262143 = b*8192 + k
  const int b = i >> 13, k = i & 8191;
  const size_t base = (size_t)(b * 4) * 8192 + k;
  const float m0 = pm[base], m1 = pm[base + 8192], m2 = pm[base + 16384], m3 = pm[base + 24576];
  const float p0 = pp[base], p1 = pp[base + 8192], p2 = pp[base + 16384], p3 = pp[base + 24576];
  const float M = fmaxf(fmaxf(m0, m1), fmaxf(m2, m3));
  float tsum = p0*__expf((m0 - M)*TT_INV) + p1*__expf((m1 - M)*TT_INV)
             + p2*__expf((m2 - M)*TT_INV) + p3*__expf((m3 - M)*TT_INV);
  tsum *= __expf(EXPMAX);                 // = t1
  shg[i] = M;
  dcg[i] = EXPMAX - __logf(tsum + SK_EPS);   // EXPMAX + ln C1,  C1 = 1/(t1+eps)
}

// -------------------- dc update from t-partial slices --------------------
// u_total = C*t, C' = C/(u+eps)  =>  dc' = dc - ln(u+eps)
__global__ __launch_bounds__(256) void updD_k(float* __restrict__ dcg,
                                              const float* __restrict__ tpart){
  const int i = blockIdx.x * 256 + threadIdx.x;   // 262144 = b*8192 + k
  const int b = i >> 13, k = i & 8191;
  const float* p = tpart + (size_t)(b * 8) * 8192 + k;
  float s = 0.f;
  #pragma unroll
  for(int j = 0; j < 8; j++) s += p[(size_t)j * 8192];
  dcg[i] -= __logf(s + SK_EPS);
}

// -------------------- wave-autonomous sinkhorn iteration --------------------
// grid 256 blocks (b*8+blk), 512 thr = 8 waves; block owns 32 rows, wave owns
// 4. No block barriers in the main loop. u in transposed LDS layout
// [j*256 + c*64 + lane] -> ds_add banks 2-way (free).
template<int LAST>
__global__ __launch_bounds__(512, 2) void iter_k(const float* __restrict__ logits,
                                                 const float* __restrict__ shg,
                                                 const float* __restrict__ dcg,
                                                 float* __restrict__ Rb,
                                                 float* __restrict__ tpart,
                                                 float* __restrict__ out,
                                                 float* __restrict__ lossacc){
  const int bid = blockIdx.x, t = threadIdx.x;
  const int b = bid >> 3, blk = bid & 7;
  const int lane = t & 63, wv = t >> 6;
  __shared__ __align__(16) float shl[8192];
  __shared__ __align__(16) float dcl[8192];
  __shared__ float u[LAST ? 4 : 8192];

  {
    const float* sp = shg + (size_t)b * 8192;
    const float* dp = dcg + (size_t)b * 8192;
    #pragma unroll
    for(int it = 0; it < 4; it++){
      const int idx = it*2048 + t*4;
      *(float4*)&shl[idx] = *(const float4*)(sp + idx);
      *(float4*)&dcl[idx] = *(const float4*)(dp + idx);
      if(!LAST) *(v4f*)&u[idx] = (v4f){0.f,0.f,0.f,0.f};
    }
  }
  __syncthreads();

  const int row0 = b*256 + blk*32 + wv*4;
  float lossw = 0.f;

  for(int rr = 0; rr < 4; rr++){
    const int row = row0 + rr;
    const float* lp = logits + (size_t)row * 8192 + lane*4;
    float4 V[32];
    #pragma unroll
    for(int j = 0; j < 32; j++) V[j] = *(const float4*)(lp + j*256);
    const float Ro = Rb[row];
    float w = 0.f;
    #pragma unroll
    for(int j = 0; j < 32; j++){
      const float4 s4 = *(const float4*)&shl[j*256 + lane*4];
      const float4 d4 = *(const float4*)&dcl[j*256 + lane*4];
      float4 e;
      e.x = __expf((V[j].x - s4.x)*TT_INV + d4.x);
      e.y = __expf((V[j].y - s4.y)*TT_INV + d4.y);
      e.z = __expf((V[j].z - s4.z)*TT_INV + d4.z);
      e.w = __expf((V[j].w - s4.w)*TT_INV + d4.w);
      w += (e.x + e.y) + (e.z + e.w);
      if(!LAST) V[j] = e;                 // keep ec for u-update
    }
    #pragma unroll
    for(int o = 32; o; o >>= 1) w += __shfl_xor(w, o);   // all lanes get w
    const float Rn = Ro / (Ro * w + SK_EPS);

    if(!LAST){
      if(lane == 0) Rb[row] = Rn;
      #pragma unroll
      for(int j = 0; j < 32; j++){
        atomicAdd(&u[j*256 +       lane], V[j].x * Rn);
        atomicAdd(&u[j*256 +  64 + lane], V[j].y * Rn);
        atomicAdd(&u[j*256 + 128 + lane], V[j].z * Rn);
        atomicAdd(&u[j*256 + 192 + lane], V[j].w * Rn);
      }
    } else {
      float mR = -FLT_MAX;
      #pragma unroll
      for(int j = 0; j < 32; j++)
        mR = fmaxf(mR, fmaxf(fmaxf(V[j].x, V[j].y), fmaxf(V[j].z, V[j].w)));
      #pragma unroll
      for(int o = 32; o; o >>= 1) mR = fmaxf(mR, __shfl_xor(mR, o));
      float pe = 0.f, sT = 0.f, sTP = 0.f;
      #pragma unroll
      for(int j = 0; j < 32; j++){
        const float4 s4 = *(const float4*)&shl[j*256 + lane*4];
        const float4 d4 = *(const float4*)&dcl[j*256 + lane*4];
        v4f a;
        a[0] = __expf((V[j].x - s4.x)*TT_INV + d4.x) * Rn;
        a[1] = __expf((V[j].y - s4.y)*TT_INV + d4.y) * Rn;
        a[2] = __expf((V[j].z - s4.z)*TT_INV + d4.z) * Rn;
        a[3] = __expf((V[j].w - s4.w)*TT_INV + d4.w) * Rn;
        __builtin_nontemporal_store(a, (v4f*)(out + (size_t)row*8192 + j*256 + lane*4));
        pe += (__expf((V[j].x - mR)*TP_INV) + __expf((V[j].y - mR)*TP_INV))
            + (__expf((V[j].z - mR)*TP_INV) + __expf((V[j].w - mR)*TP_INV));
        sT += (a[0] + a[1]) + (a[2] + a[3]);
        sTP += (a[0]*V[j].x + a[1]*V[j].y) + (a[2]*V[j].z + a[3]*V[j].w);
      }
      pe = wredsum(pe); sT = wredsum(sT); sTP = wredsum(sTP);
      if(lane == 0)
        lossw += TP_INV*sTP - (mR*TP_INV + __logf(pe))*sT;
    }
  }

  if(LAST){
    if(lane == 0) atomicAdd(lossacc, lossw);
  } else {
    __syncthreads();
    // flush transposed u -> k-ordered tpart slice (coalesced f4 stores)
    #pragma unroll
    for(int it = 0; it < 4; it++){
      const int j = it*8 + (t >> 6), l = t & 63;
      v4f val = { u[j*256 +       l], u[j*256 +  64 + l],
                  u[j*256 + 128 + l], u[j*256 + 192 + l] };
      *(v4f*)(tpart + (size_t)bid*8192 + it*2048 + t*4) = val;
    }
  }
}

__global__ void finscale_k(const float* __restrict__ lossacc, float* __restrict__ dst){
  dst[0] = -lossacc[0] * (1.0f / 8192.0f);
}

// ---------------------------------------------------------------------------
extern "C" void kernel_launch(void* const* d_in, const int* in_sizes, int n_in,
                              void* d_out, int out_size, void* d_ws, size_t ws_size,
                              hipStream_t stream){
  const float* x = (const float*)d_in[0];   // [32,256,1024]
  const float* W = (const float*)d_in[1];   // [8192,1024]
  float* out = (float*)d_out;               // 32*256*8192 assignments + 1 loss

  char* ws = (char*)d_ws;
  unsigned short* xb   = (unsigned short*)(ws);                 // 16 MB bf16
  unsigned short* Wb   = (unsigned short*)(ws + 16777216);      // 16 MB bf16
  float*    logits     = (float*)   (ws + 33554432);            // 256 MB f32
  float*    shg        = (float*)   (ws + 301989888);           // 1 MB
  float*    dcg        = (float*)   (ws + 303038464);           // 1 MB
  float*    Rb         = (float*)   (ws + 304087040);           // 32 KB
  float*    lossacc    = (float*)   (ws + 304119808);           // 4 B
  // scratch hosted in d_out (dead until iter<1> writes it):
  float*    pp         = out;                                   // 4 MB [128][8192]
  float*    pm         = out + 1048576;                         // 4 MB [128][8192]
  float*    tpart      = out;                                   // 8 MB [256][8192]

  init_k   <<<32, 256, 0, stream>>>(Rb, lossacc);
  norm_x_k <<<8192, 256, 0, stream>>>(x, xb);
  conv_w_k <<<8192, 256, 0, stream>>>(W, Wb);
  gemm_bt_k<<<dim3(64, 64), 256, 0, stream>>>(xb, Wb, logits, pp, pm);
  merge_k  <<<1024, 256, 0, stream>>>(pp, pm, shg, dcg);        // sh + dc1
  iter_k<0><<<256, 512, 0, stream>>>(logits, shg, dcg, Rb, tpart,
                                     (float*)nullptr, (float*)nullptr);
  updD_k   <<<1024, 256, 0, stream>>>(dcg, tpart);              // dc2
  iter_k<0><<<256, 512, 0, stream>>>(logits, shg, dcg, Rb, tpart,
                                     (float*)nullptr, (float*)nullptr);
  updD_k   <<<1024, 256, 0, stream>>>(dcg, tpart);              // dc3
  iter_k<1><<<256, 512, 0, stream>>>(logits, shg, dcg, Rb,
                                     (float*)nullptr, out, lossacc);
  finscale_k<<<1, 1, 0, stream>>>(lossacc, out + (size_t)(out_size - 1));
}